// Round 12
// baseline (676.772 us; speedup 1.0000x reference)
//
#include <hip/hip_runtime.h>

#define T_TOK 4096
#define S_SEQ 2048
#define H_DIM 1024
#define H3    3072
#define NHEAD 8
#define DHEAD 128
#define F_DIM 4096
#define NEXP  8
#define MAX_RB 72
#define NSLOT 9216

typedef __bf16 bf16x8 __attribute__((ext_vector_type(8)));
typedef float  f32x4  __attribute__((ext_vector_type(4)));
typedef __attribute__((address_space(1))) const unsigned int* gas1_t;
typedef __attribute__((address_space(3))) unsigned int* las3_t;

__device__ __forceinline__ unsigned short f2bf(float f){
  unsigned int u = __builtin_bit_cast(unsigned int, f);
  u += 0x7fffu + ((u>>16)&1u);          // RTNE to bf16 (no NaN inputs here)
  return (unsigned short)(u>>16);
}
__device__ __forceinline__ float bf2f(unsigned short h){
  unsigned int u = ((unsigned int)h)<<16;
  return __builtin_bit_cast(float, u);
}
__device__ __forceinline__ f32x4 MF(bf16x8 a, bf16x8 b, f32x4 c){
  return __builtin_amdgcn_mfma_f32_16x16x32_bf16(a,b,c,0,0,0);
}
__device__ __forceinline__ void gload16(const void* g, void* l){
  __builtin_amdgcn_global_load_lds((gas1_t)g, (las3_t)l, 16, 0, 0);
}
__device__ __forceinline__ float blockReduceSum(float v){
  __shared__ float sh_red[4];
  #pragma unroll
  for(int o=32;o>0;o>>=1) v += __shfl_down(v,o,64);
  int w = threadIdx.x>>6;
  if((threadIdx.x&63)==0) sh_red[w]=v;
  __syncthreads();
  float tot = sh_red[0]+sh_red[1]+sh_red[2]+sh_red[3];
  __syncthreads();
  return tot;
}

// ---------------- LayerNorm 1: x -> xa split (bf16 hi/lo) ----------------
__global__ __launch_bounds__(256) void k_ln_split(const float* __restrict__ x,
    const float* __restrict__ g, const float* __restrict__ bta,
    unsigned short* __restrict__ hi, unsigned short* __restrict__ lo){
  int t = blockIdx.x, tid = threadIdx.x;
  float4 v = reinterpret_cast<const float4*>(x + (size_t)t*H_DIM)[tid];
  float mean = blockReduceSum(v.x+v.y+v.z+v.w) * (1.0f/H_DIM);
  float d0=v.x-mean,d1=v.y-mean,d2=v.z-mean,d3=v.w-mean;
  float var = blockReduceSum(d0*d0+d1*d1+d2*d2+d3*d3) * (1.0f/H_DIM);
  float rstd = rsqrtf(var + 1e-5f);
  float4 gv = reinterpret_cast<const float4*>(g)[tid];
  float4 bv = reinterpret_cast<const float4*>(bta)[tid];
  float o0=d0*rstd*gv.x+bv.x, o1=d1*rstd*gv.y+bv.y, o2=d2*rstd*gv.z+bv.z, o3=d3*rstd*gv.w+bv.w;
  size_t base = (size_t)t*H_DIM + tid*4;
  unsigned short h0=f2bf(o0),h1=f2bf(o1),h2=f2bf(o2),h3=f2bf(o3);
  *reinterpret_cast<ushort4*>(hi+base) = make_ushort4(h0,h1,h2,h3);
  *reinterpret_cast<ushort4*>(lo+base) = make_ushort4(
      f2bf(o0-bf2f(h0)), f2bf(o1-bf2f(h1)), f2bf(o2-bf2f(h2)), f2bf(o3-bf2f(h3)));
}

// ---------------- weight split fp32 -> bf16 hi/lo ----------------
__global__ __launch_bounds__(256) void k_wsplit(const float* __restrict__ w,
    unsigned short* __restrict__ hi, unsigned short* __restrict__ lo, int n4){
  int i = blockIdx.x*256 + threadIdx.x;
  if(i>=n4) return;
  float4 v = reinterpret_cast<const float4*>(w)[i];
  size_t base = (size_t)i*4;
  unsigned short h0=f2bf(v.x),h1=f2bf(v.y),h2=f2bf(v.z),h3=f2bf(v.w);
  *reinterpret_cast<ushort4*>(hi+base) = make_ushort4(h0,h1,h2,h3);
  *reinterpret_cast<ushort4*>(lo+base) = make_ushort4(
      f2bf(v.x-bf2f(h0)), f2bf(v.y-bf2f(h1)), f2bf(v.z-bf2f(h2)), f2bf(v.w-bf2f(h3)));
}

// ---------------- weight convert fp32 -> bf16 (hi only) ----------------
__global__ __launch_bounds__(256) void k_wconv(const float* __restrict__ w,
    unsigned short* __restrict__ hi, int n4){
  int i = blockIdx.x*256 + threadIdx.x;
  if(i>=n4) return;
  float4 v = reinterpret_cast<const float4*>(w)[i];
  *reinterpret_cast<ushort4*>(hi + (size_t)i*4) =
      make_ushort4(f2bf(v.x), f2bf(v.y), f2bf(v.z), f2bf(v.w));
}

// ---------------- split GEMM: C = A*B^T (+bias [+resid]) --------------------
template<int EPI>
__global__ __launch_bounds__(256) void k_gemm_split(
    const unsigned short* __restrict__ Ah, const unsigned short* __restrict__ Al,
    const unsigned short* __restrict__ Bh, const unsigned short* __restrict__ Bl,
    const float* __restrict__ bias, const float* __restrict__ resid,
    unsigned short* __restrict__ Chi, unsigned short* __restrict__ Clo,
    float* __restrict__ Cf, int N, int Kd){
  int m0 = blockIdx.y*128, n0 = blockIdx.x*128;
  int tid=threadIdx.x, wid=tid>>6, lane=tid&63, lr=lane&15, lg=lane>>4;
  int wr=wid>>1, wc=wid&1;
  __shared__ unsigned short tAh[4096], tAl[4096], tBh[4096], tBl[4096];
  f32x4 acc[4][4] = {};
  for(int k0=0;k0<Kd;k0+=32){
    #pragma unroll
    for(int i=0;i<2;i++){
      int p = i*256 + tid;
      int row = p>>2, pc = p&3;
      int lc = pc ^ ((row>>1)&3);                    // source pre-swizzle (rule #21)
      size_t go = (size_t)row*Kd + k0 + lc*8;
      int lb = (i*256 + wid*64)*8;
      gload16(Ah + (size_t)m0*Kd + go, tAh + lb);
      gload16(Al + (size_t)m0*Kd + go, tAl + lb);
      gload16(Bh + (size_t)n0*Kd + go, tBh + lb);
      gload16(Bl + (size_t)n0*Kd + go, tBl + lb);
    }
    asm volatile("s_waitcnt vmcnt(0)" ::: "memory");
    __syncthreads();
    bf16x8 ah[4], al[4], bh[4], bl[4];
    #pragma unroll
    for(int q=0;q<4;q++){
      int ra = wr*64+q*16+lr;
      int ia = ra*32 + ((lg ^ ((ra>>1)&3))<<3);
      ah[q] = *reinterpret_cast<const bf16x8*>(&tAh[ia]);
      al[q] = *reinterpret_cast<const bf16x8*>(&tAl[ia]);
      int rb = wc*64+q*16+lr;
      int ib = rb*32 + ((lg ^ ((rb>>1)&3))<<3);
      bh[q] = *reinterpret_cast<const bf16x8*>(&tBh[ib]);
      bl[q] = *reinterpret_cast<const bf16x8*>(&tBl[ib]);
    }
    #pragma unroll
    for(int mf=0;mf<4;mf++)
      #pragma unroll
      for(int nf=0;nf<4;nf++){
        acc[mf][nf] = MF(ah[mf], bh[nf], acc[mf][nf]);
        acc[mf][nf] = MF(ah[mf], bl[nf], acc[mf][nf]);
        acc[mf][nf] = MF(al[mf], bh[nf], acc[mf][nf]);
      }
    __syncthreads();
  }
  #pragma unroll
  for(int mf=0;mf<4;mf++)
    #pragma unroll
    for(int nf=0;nf<4;nf++)
      #pragma unroll
      for(int r=0;r<4;r++){
        int row = m0 + wr*64 + mf*16 + lg*4 + r;
        int col = n0 + wc*64 + nf*16 + lr;
        float v = acc[mf][nf][r] + bias[col];
        size_t idx = (size_t)row*N + col;
        if(EPI==0){
          unsigned short hb = f2bf(v);
          Chi[idx]=hb; Clo[idx]=f2bf(v-bf2f(hb));
        } else {
          Cf[idx] = v + resid[idx];
        }
      }
}

// ---------------- V transpose: qkv v-cols -> vt[bh][d][s] hi/lo ----------------
__global__ __launch_bounds__(256) void k_vtrans(const unsigned short* __restrict__ qh,
    const unsigned short* __restrict__ ql,
    unsigned short* __restrict__ vth, unsigned short* __restrict__ vtl){
  int bh = blockIdx.z, d0 = blockIdx.y*32, s0 = blockIdx.x*32;
  int b = bh>>3, hh = bh&7;
  int tid=threadIdx.x;
  __shared__ unsigned short th[32][40], tl[32][40];
  int sr = tid>>3, dc = (tid&7)*4;
  size_t src = ((size_t)(b*S_SEQ + s0 + sr))*H3 + 2*H_DIM + hh*DHEAD + d0 + dc;
  *reinterpret_cast<ushort4*>(&th[sr][dc]) = *reinterpret_cast<const ushort4*>(qh+src);
  *reinterpret_cast<ushort4*>(&tl[sr][dc]) = *reinterpret_cast<const ushort4*>(ql+src);
  __syncthreads();
  int dr = tid>>3, sc = (tid&7)*4;
  size_t dst = ((size_t)(bh*DHEAD) + d0+dr)*S_SEQ + s0 + sc;
  *reinterpret_cast<ushort4*>(vth+dst) = make_ushort4(th[sc][dr],th[sc+1][dr],th[sc+2][dr],th[sc+3][dr]);
  *reinterpret_cast<ushort4*>(vtl+dst) = make_ushort4(tl[sc][dr],tl[sc+1][dr],tl[sc+2][dr],tl[sc+3][dr]);
}

// ---------------- flash attention (split precision, swapped-QK, KV-split partials) ----------------
// Single-buffered 48 KB LDS so 2 blocks co-reside per CU (cross-block latency hiding).
__global__ __launch_bounds__(256,2) void k_attn(const unsigned short* __restrict__ qkv_hi,
    const unsigned short* __restrict__ qkv_lo,
    const unsigned short* __restrict__ vt_hi, const unsigned short* __restrict__ vt_lo,
    float* __restrict__ opb, float* __restrict__ mlb, int kv_span){
  const float SCALE = 0.08838834764831843f;   // 1/sqrt(128)
  int qb = blockIdx.x, bh = blockIdx.y, zz = blockIdx.z;
  int b = bh>>3, hh = bh&7;
  int kvbase = zz*kv_span, kvend = kvbase + kv_span;
  int tid=threadIdx.x, wid=tid>>6, lane=tid&63, lr=lane&15, lg=lane>>4;
  __shared__ unsigned short kh[4096], kl[4096], vh[4096], vl[4096];   // 32 KB
  __shared__ unsigned short ph[4][1024], pl[4][1024];                 // 16 KB
  int row0 = qb*128 + wid*32;            // wave's first q row (wave owns 32 rows)
  // Q fragments in registers: B-operand layout (col=qrow=lr, k-slice lg*8)
  bf16x8 qh_[2][4], ql_[2][4];
  #pragma unroll
  for(int j=0;j<2;j++){
    size_t qbase = ((size_t)(b*S_SEQ) + row0 + j*16 + lr)*H3 + hh*DHEAD;
    #pragma unroll
    for(int kk=0;kk<4;kk++){
      qh_[j][kk] = *reinterpret_cast<const bf16x8*>(qkv_hi + qbase + kk*32 + lg*8);
      ql_[j][kk] = *reinterpret_cast<const bf16x8*>(qkv_lo + qbase + kk*32 + lg*8);
    }
  }
  f32x4 o_acc[2][8] = {};
  float mrun[2] = {-1e30f,-1e30f};
  float lrun[2] = {0.f,0.f};

  auto STAGE = [&](int kv0){
    #pragma unroll
    for(int i=0;i<2;i++){
      int p = i*256 + tid;
      int lb = (i*256 + wid*64)*8;
      { // K tile [32 keys][128 d], 16B-chunk XOR source pre-swizzle
        int krow = p>>4, pc = p&15;
        int lc = (pc&8)|((pc&7)^(krow&7));
        size_t go = ((size_t)(b*S_SEQ + kv0 + krow))*H3 + H_DIM + hh*DHEAD + lc*8;
        gload16(qkv_hi + go, &kh[lb]);
        gload16(qkv_lo + go, &kl[lb]);
      }
      { // V tile [128 d][32 keys]
        int vrow = p>>2, pc = p&3;
        int lc = pc ^ ((vrow>>1)&3);
        size_t gv = ((size_t)(bh*DHEAD) + vrow)*S_SEQ + kv0 + lc*8;
        gload16(vt_hi + gv, &vh[lb]);
        gload16(vt_lo + gv, &vl[lb]);
      }
    }
  };

  for(int kv0=kvbase; kv0<kvend; kv0+=32){
    STAGE(kv0);
    asm volatile("s_waitcnt vmcnt(0)" ::: "memory");
    __syncthreads();
    // ---- QK^T swapped: S[key][qrow] = mfma(K, Q), split 3-product ----
    f32x4 s0[2] = {}, s1[2] = {};              // keys 0-15 / 16-31, per q-block
    #pragma unroll
    for(int kk=0;kk<4;kk++){
      int c = kk*4+lg;
      int phys = (c&8)|((c&7)^(lr&7));
      bf16x8 kah = *reinterpret_cast<const bf16x8*>(&kh[lr*128 + phys*8]);
      bf16x8 kal = *reinterpret_cast<const bf16x8*>(&kl[lr*128 + phys*8]);
      bf16x8 kbh = *reinterpret_cast<const bf16x8*>(&kh[(16+lr)*128 + phys*8]);
      bf16x8 kbl = *reinterpret_cast<const bf16x8*>(&kl[(16+lr)*128 + phys*8]);
      #pragma unroll
      for(int j=0;j<2;j++){
        s0[j] = MF(kah, qh_[j][kk], s0[j]);
        s0[j] = MF(kah, ql_[j][kk], s0[j]);
        s0[j] = MF(kal, qh_[j][kk], s0[j]);
        s1[j] = MF(kbh, qh_[j][kk], s1[j]);
        s1[j] = MF(kbh, ql_[j][kk], s1[j]);
        s1[j] = MF(kbl, qh_[j][kk], s1[j]);
      }
    }
    // ---- online softmax: lane owns qrow=lr, 8 keys in regs ----
    float sc[2][8]; float mt[2];
    #pragma unroll
    for(int j=0;j<2;j++){
      #pragma unroll
      for(int r=0;r<4;r++){ sc[j][r] = s0[j][r]*SCALE; sc[j][4+r] = s1[j][r]*SCALE; }
      float m_ = fmaxf(fmaxf(fmaxf(sc[j][0],sc[j][1]),fmaxf(sc[j][2],sc[j][3])),
                       fmaxf(fmaxf(sc[j][4],sc[j][5]),fmaxf(sc[j][6],sc[j][7])));
      m_ = fmaxf(m_, __shfl_xor(m_,16,64));
      m_ = fmaxf(m_, __shfl_xor(m_,32,64));
      mt[j] = m_;
    }
    // defer-max (T13): skip O-rescale unless tile max grew past threshold
    int skip = __all((mt[0] <= mrun[0]+8.0f) && (mt[1] <= mrun[1]+8.0f));
    if(!skip){
      #pragma unroll
      for(int j=0;j<2;j++){
        float mn = fmaxf(mrun[j], mt[j]);
        float rs = __expf(mrun[j]-mn);
        lrun[j] *= rs; mrun[j] = mn;
        #pragma unroll
        for(int nf2=0;nf2<8;nf2++){
          f32x4 t = o_acc[j][nf2];
          t[0]*=rs; t[1]*=rs; t[2]*=rs; t[3]*=rs;
          o_acc[j][nf2] = t;
        }
      }
    }
    #pragma unroll
    for(int j=0;j<2;j++){
      float ssum = 0.f;
      #pragma unroll
      for(int i=0;i<8;i++){ sc[j][i] = __expf(sc[j][i]-mrun[j]); ssum += sc[j][i]; }
      ssum += __shfl_xor(ssum,16,64);
      ssum += __shfl_xor(ssum,32,64);
      lrun[j] += ssum;
      // pack P hi/lo, swizzled b64 writes: row qrow=lr, keys lg*4..+3 and 16+lg*4..+3
      unsigned short hbk[8], lbk[8];
      #pragma unroll
      for(int i=0;i<8;i++){ hbk[i]=f2bf(sc[j][i]); lbk[i]=f2bf(sc[j][i]-bf2f(hbk[i])); }
      int half = (lg&1)*4;
      int a0 = j*512 + lr*32 + (((lg>>1)^(lr&3))<<3) + half;
      int a1 = j*512 + lr*32 + ((((lg>>1)+2)^(lr&3))<<3) + half;
      *reinterpret_cast<ushort4*>(&ph[wid][a0]) = make_ushort4(hbk[0],hbk[1],hbk[2],hbk[3]);
      *reinterpret_cast<ushort4*>(&pl[wid][a0]) = make_ushort4(lbk[0],lbk[1],lbk[2],lbk[3]);
      *reinterpret_cast<ushort4*>(&ph[wid][a1]) = make_ushort4(hbk[4],hbk[5],hbk[6],hbk[7]);
      *reinterpret_cast<ushort4*>(&pl[wid][a1]) = make_ushort4(lbk[4],lbk[5],lbk[6],lbk[7]);
    }
    // ---- PV: O^T[d][qrow] = mfma(V, P), split 3-product ----
    bf16x8 pbh[2], pbl[2];
    #pragma unroll
    for(int j=0;j<2;j++){
      int pp = (lg^(lr&3))<<3;
      pbh[j] = *reinterpret_cast<const bf16x8*>(&ph[wid][j*512 + lr*32 + pp]);
      pbl[j] = *reinterpret_cast<const bf16x8*>(&pl[wid][j*512 + lr*32 + pp]);
    }
    #pragma unroll
    for(int nf2=0;nf2<8;nf2++){
      int d = nf2*16 + lr;
      int vp = (lg ^ ((d>>1)&3))<<3;
      bf16x8 vah = *reinterpret_cast<const bf16x8*>(&vh[d*32 + vp]);
      bf16x8 val = *reinterpret_cast<const bf16x8*>(&vl[d*32 + vp]);
      #pragma unroll
      for(int j=0;j<2;j++){
        o_acc[j][nf2] = MF(vah, pbh[j], o_acc[j][nf2]);
        o_acc[j][nf2] = MF(vah, pbl[j], o_acc[j][nf2]);
        o_acc[j][nf2] = MF(val, pbh[j], o_acc[j][nf2]);
      }
    }
    __syncthreads();   // all reads of kh/kl/vh/vl done before next STAGE overwrites
  }
  // ---- epilogue: write unnormalized fp32 partials + (m,l) per row ----
  #pragma unroll
  for(int j=0;j<2;j++){
    int srow = row0 + j*16 + lr;
    size_t obase = (((size_t)zz*16 + bh)*S_SEQ + srow)*(size_t)DHEAD;
    #pragma unroll
    for(int nf2=0;nf2<8;nf2++){
      *reinterpret_cast<f32x4*>(&opb[obase + nf2*16 + lg*4]) = o_acc[j][nf2];
    }
    if(lg==0){
      *reinterpret_cast<float2*>(&mlb[(((size_t)zz*16 + bh)*S_SEQ + srow)*2]) =
          make_float2(mrun[j], lrun[j]);
    }
  }
}

// ---------------- merge KV-split partials -> attn out (bf16 hi/lo) ----------------
__global__ __launch_bounds__(256) void k_amerge(const float* __restrict__ opb,
    const float* __restrict__ mlb, int nz,
    unsigned short* __restrict__ o_hi, unsigned short* __restrict__ o_lo){
  int bh = blockIdx.y, b = bh>>3, hh = bh&7;
  int r = threadIdx.x>>4;                 // 0..15 row within block
  int c = (threadIdx.x&15)*8;             // 0..120 col (d)
  int srow = blockIdx.x*16 + r;
  float mz[4], lz[4];
  float m = -1e30f;
  for(int z=0;z<nz;z++){
    const float* mlp = mlb + (((size_t)z*16 + bh)*S_SEQ + srow)*2;
    mz[z]=mlp[0]; lz[z]=mlp[1];
    m = fmaxf(m, mz[z]);
  }
  float L = 0.f, w[4];
  for(int z=0;z<nz;z++){ w[z] = __expf(mz[z]-m); L += lz[z]*w[z]; }
  float linv = 1.0f/L;
  float acc[8] = {0,0,0,0,0,0,0,0};
  for(int z=0;z<nz;z++){
    const float* o = opb + (((size_t)z*16 + bh)*S_SEQ + srow)*(size_t)DHEAD + c;
    float4 a = *reinterpret_cast<const float4*>(o);
    float4 bq = *reinterpret_cast<const float4*>(o+4);
    acc[0]+=a.x*w[z]; acc[1]+=a.y*w[z]; acc[2]+=a.z*w[z]; acc[3]+=a.w*w[z];
    acc[4]+=bq.x*w[z]; acc[5]+=bq.y*w[z]; acc[6]+=bq.z*w[z]; acc[7]+=bq.w*w[z];
  }
  size_t idx = ((size_t)(b*S_SEQ)+srow)*H_DIM + hh*DHEAD + c;
  unsigned short hp[8], lp[8];
  #pragma unroll
  for(int i=0;i<8;i++){
    float v = acc[i]*linv;
    hp[i]=f2bf(v); lp[i]=f2bf(v-bf2f(hp[i]));
  }
  *reinterpret_cast<ushort4*>(o_hi+idx)   = make_ushort4(hp[0],hp[1],hp[2],hp[3]);
  *reinterpret_cast<ushort4*>(o_hi+idx+4) = make_ushort4(hp[4],hp[5],hp[6],hp[7]);
  *reinterpret_cast<ushort4*>(o_lo+idx)   = make_ushort4(lp[0],lp[1],lp[2],lp[3]);
  *reinterpret_cast<ushort4*>(o_lo+idx+4) = make_ushort4(lp[4],lp[5],lp[6],lp[7]);
}

// ---------------- LayerNorm 2 + router ----------------
__global__ __launch_bounds__(256) void k_ln2_router(const float* __restrict__ h,
    const float* __restrict__ g, const float* __restrict__ bt, const float* __restrict__ rw,
    unsigned short* __restrict__ ybf, int* __restrict__ route_e, float* __restrict__ route_w){
  int t = blockIdx.x, tid = threadIdx.x;
  float4 v = reinterpret_cast<const float4*>(h + (size_t)t*H_DIM)[tid];
  float mean = blockReduceSum(v.x+v.y+v.z+v.w) * (1.0f/H_DIM);
  float d0=v.x-mean,d1=v.y-mean,d2=v.z-mean,d3=v.w-mean;
  float var = blockReduceSum(d0*d0+d1*d1+d2*d2+d3*d3) * (1.0f/H_DIM);
  float rstd = rsqrtf(var + 1e-5f);
  float4 gv = reinterpret_cast<const float4*>(g)[tid];
  float4 bv = reinterpret_cast<const float4*>(bt)[tid];
  float o0=d0*rstd*gv.x+bv.x, o1=d1*rstd*gv.y+bv.y, o2=d2*rstd*gv.z+bv.z, o3=d3*rstd*gv.w+bv.w;
  size_t base = (size_t)t*H_DIM + tid*4;
  *reinterpret_cast<ushort4*>(ybf+base) = make_ushort4(f2bf(o0),f2bf(o1),f2bf(o2),f2bf(o3));
  float part[8];
  #pragma unroll
  for(int e=0;e<8;e++){
    float4 r = reinterpret_cast<const float4*>(rw + e*H_DIM)[tid];
    part[e] = o0*r.x + o1*r.y + o2*r.z + o3*r.w;
  }
  __shared__ float sm[32];
  #pragma unroll
  for(int e=0;e<8;e++){
    float p = part[e];
    #pragma unroll
    for(int o=32;o>0;o>>=1) p += __shfl_down(p,o,64);
    if((tid&63)==0) sm[(tid>>6)*8+e] = p;
  }
  __syncthreads();
  if(tid==0){
    float lgt[8];
    #pragma unroll
    for(int e=0;e<8;e++) lgt[e] = sm[e]+sm[8+e]+sm[16+e]+sm[24+e];
    float mx = lgt[0];
    #pragma unroll
    for(int e=1;e<8;e++) mx = fmaxf(mx, lgt[e]);
    float ex[8], ssum=0.f;
    #pragma unroll
    for(int e=0;e<8;e++){ ex[e]=__expf(lgt[e]-mx); ssum+=ex[e]; }
    float inv = 1.0f/ssum;
    int e0=0; float p0=ex[0];
    for(int e=1;e<8;e++) if(ex[e]>p0){p0=ex[e];e0=e;}
    int e1=-1; float p1=-1.0f;
    for(int e=0;e<8;e++) if(e!=e0 && ex[e]>p1){p1=ex[e];e1=e;}
    route_e[2*t]=e0; route_e[2*t+1]=e1;
    route_w[2*t]=p0*inv; route_w[2*t+1]=p1*inv;
  }
}

// ---------------- routing compaction (single block) ----------------
__global__ __launch_bounds__(256) void k_compact(const int* __restrict__ route_e,
    const float* __restrict__ route_w, int* __restrict__ tok_of_slot,
    float* __restrict__ w_of_slot, int* __restrict__ slot_of_tok,
    int* __restrict__ rb_expert, int* __restrict__ rb_base){
  __shared__ int cnt[8], off[8], pos[8];
  int tid = threadIdx.x;
  if(tid<8){ cnt[tid]=0; pos[tid]=0; }
  __syncthreads();
  for(int t=tid;t<T_TOK;t+=256){
    atomicAdd(&cnt[route_e[2*t]],1);
    atomicAdd(&cnt[route_e[2*t+1]],1);
  }
  __syncthreads();
  if(tid==0){
    int o=0;
    for(int e=0;e<8;e++){ off[e]=o; o += ((cnt[e]+127)>>7)<<7; }
    int rb=0;
    for(int e=0;e<8;e++){
      int nrb = (cnt[e]+127)>>7;
      for(int r=0;r<nrb;r++){ rb_expert[rb]=e; rb_base[rb]=off[e]+r*128; rb++; }
    }
    for(;rb<MAX_RB;rb++){ rb_expert[rb]=-1; rb_base[rb]=0; }
  }
  __syncthreads();
  for(int s=tid;s<NSLOT;s+=256){ tok_of_slot[s]=0; w_of_slot[s]=0.0f; }
  __syncthreads();
  for(int t=tid;t<T_TOK;t+=256){
    int e0=route_e[2*t], e1=route_e[2*t+1];
    int s0 = off[e0] + atomicAdd(&pos[e0],1);
    tok_of_slot[s0]=t; w_of_slot[s0]=route_w[2*t]; slot_of_tok[2*t]=s0;
    int s1 = off[e1] + atomicAdd(&pos[e1],1);
    tok_of_slot[s1]=t; w_of_slot[s1]=route_w[2*t+1]; slot_of_tok[2*t+1]=s1;
  }
}

// ---------------- expert GEMMs (R5 inner loop; XCD-grouped dispatch remap on both) ----
// Mapping: xcd = lin%8 (HW round-robin). Each XCD gets 9 CONTIGUOUS rowblocks,
// n0 sweeping fastest -> gathered A rows L2-local AND expert B panels quasi-local.
template<bool FC1, bool PRE>
__global__ __launch_bounds__(256) void k_fc(const unsigned short* __restrict__ Abuf,
    const float* __restrict__ W, const unsigned short* __restrict__ Wbf,
    const float* __restrict__ bias,
    const int* __restrict__ rb_expert, const int* __restrict__ rb_base,
    const int* __restrict__ tok_of_slot, const float* __restrict__ w_of_slot,
    unsigned short* __restrict__ he_out, float* __restrict__ oew_out){
  int rb, n0;
  if(FC1){
    // grid (32, 72): lin = y*32 + x  (x fastest in dispatch order)
    int lin = blockIdx.y*32 + blockIdx.x;
    int xcd = lin & 7, idx = lin >> 3;     // idx 0..287
    n0 = (idx & 31) * 128;                 // n-block fastest within XCD
    rb = xcd*9 + (idx >> 5);               // 9 contiguous rowblocks per XCD
  } else {
    // grid (8, 72): lin = y*8 + x
    int lin = blockIdx.y*8 + blockIdx.x;
    int xcd = lin & 7, idx = lin >> 3;     // idx 0..71
    n0 = (idx & 7) * 128;
    rb = xcd*9 + (idx >> 3);
  }
  int e = rb_expert[rb];
  if(e<0) return;
  int base = rb_base[rb];
  const int Kd = FC1 ? H_DIM : F_DIM;
  const int Nd = FC1 ? F_DIM : H_DIM;
  int tid=threadIdx.x, wid=tid>>6, lane=tid&63, lr=lane&15, lg=lane>>4;
  int wr=wid>>1, wc=wid&1;
  __shared__ unsigned short tA[4096], tB[4096];
  size_t arow_src[2];
  #pragma unroll
  for(int i=0;i<2;i++){
    int row = i*64 + (tid>>2);
    if(FC1){ int tok = tok_of_slot[base+row]; arow_src[i] = (size_t)tok*H_DIM; }
    else   { arow_src[i] = (size_t)(base+row)*F_DIM; }
  }
  const float* Wp = W + (size_t)e*F_DIM*H_DIM;
  const unsigned short* Wbp = Wbf + (size_t)e*F_DIM*H_DIM;
  f32x4 acc[4][4] = {};
  for(int k0=0;k0<Kd;k0+=32){
    #pragma unroll
    for(int i=0;i<2;i++){
      int p = i*256+tid; int row=p>>2, pc=p&3;
      int lc = pc ^ ((row>>1)&3);
      gload16(Abuf + arow_src[i] + k0 + lc*8, tA + (i*256+wid*64)*8);
      if(PRE){
        gload16(Wbp + (size_t)(n0+row)*Kd + k0 + lc*8, tB + (i*256+wid*64)*8);
      }
    }
    if(!PRE){
      #pragma unroll
      for(int j=0;j<4;j++){
        int f = tid*16 + j*4; int row=f>>5; int kin=f&31;
        float4 wv = *reinterpret_cast<const float4*>(Wp + (size_t)(n0+row)*Kd + k0 + kin);
        int c16 = kin>>3, half=(kin>>2)&1;
        int phys = c16 ^ ((row>>1)&3);
        *reinterpret_cast<ushort4*>(&tB[row*32 + phys*8 + half*4]) =
            make_ushort4(f2bf(wv.x), f2bf(wv.y), f2bf(wv.z), f2bf(wv.w));
      }
    }
    asm volatile("s_waitcnt vmcnt(0)" ::: "memory");
    __syncthreads();
    bf16x8 af[4], bfr[4];
    #pragma unroll
    for(int q=0;q<4;q++){
      int ra = wr*64+q*16+lr;
      af[q] = *reinterpret_cast<const bf16x8*>(&tA[ra*32 + ((lg ^ ((ra>>1)&3))<<3)]);
      int rbw = wc*64+q*16+lr;
      bfr[q] = *reinterpret_cast<const bf16x8*>(&tB[rbw*32 + ((lg ^ ((rbw>>1)&3))<<3)]);
    }
    #pragma unroll
    for(int mf=0;mf<4;mf++)
      #pragma unroll
      for(int nf=0;nf<4;nf++)
        acc[mf][nf] = MF(af[mf], bfr[nf], acc[mf][nf]);
    __syncthreads();
  }
  #pragma unroll
  for(int mf=0;mf<4;mf++)
    #pragma unroll
    for(int nf=0;nf<4;nf++)
      #pragma unroll
      for(int r=0;r<4;r++){
        int lrow = wr*64+mf*16+lg*4+r;
        int col = n0 + wc*64+nf*16+lr;
        float v = acc[mf][nf][r] + bias[(size_t)e*Nd + col];
        if(FC1){
          float sv = v/(1.0f+__expf(-v));          // silu
          he_out[(size_t)(base+lrow)*F_DIM + col] = f2bf(sv);
        } else {
          oew_out[(size_t)(base+lrow)*H_DIM + col] = w_of_slot[base+lrow]*v;
        }
      }
}

// ---------------- combine: out = h + oe[slot0] + oe[slot1] ----------------
__global__ __launch_bounds__(256) void k_combine(const float* __restrict__ h,
    const float* __restrict__ oew, const int* __restrict__ slot_of_tok,
    float* __restrict__ out){
  int t = blockIdx.x, tid=threadIdx.x;
  int s0 = slot_of_tok[2*t], s1 = slot_of_tok[2*t+1];
  float4 hv = reinterpret_cast<const float4*>(h + (size_t)t*H_DIM)[tid];
  float4 a = reinterpret_cast<const float4*>(oew + (size_t)s0*H_DIM)[tid];
  float4 b = reinterpret_cast<const float4*>(oew + (size_t)s1*H_DIM)[tid];
  float4 o = make_float4(hv.x+a.x+b.x, hv.y+a.y+b.y, hv.z+a.z+b.z, hv.w+a.w+b.w);
  reinterpret_cast<float4*>(out + (size_t)t*H_DIM)[tid] = o;
}

extern "C" void kernel_launch(void* const* d_in, const int* in_sizes, int n_in,
                              void* d_out, int out_size, void* d_ws, size_t ws_size,
                              hipStream_t stream){
  const float* x    = (const float*)d_in[0];
  const float* ln1g = (const float*)d_in[1];
  const float* ln1b = (const float*)d_in[2];
  const float* ln2g = (const float*)d_in[3];
  const float* ln2b = (const float*)d_in[4];
  const float* wqkv = (const float*)d_in[5];
  const float* bqkv = (const float*)d_in[6];
  const float* wout = (const float*)d_in[7];
  const float* bout = (const float*)d_in[8];
  const float* rw   = (const float*)d_in[9];
  const float* fc1w = (const float*)d_in[10];
  const float* fc1b = (const float*)d_in[11];
  const float* fc2w = (const float*)d_in[12];
  const float* fc2b = (const float*)d_in[13];
  char* ws = (char*)d_ws;

  size_t off_ = 0;
  auto AL = [&](size_t bytes){ size_t r = off_; off_ = (off_ + bytes + 255) & ~(size_t)255; return r; };
  // --- phase-A region (dead before MoE) ---
  size_t o_xa_hi = AL((size_t)T_TOK*H_DIM*2), o_xa_lo = AL((size_t)T_TOK*H_DIM*2);
  size_t o_wq_hi = AL((size_t)H3*H_DIM*2),    o_wq_lo = AL((size_t)H3*H_DIM*2);
  size_t o_wo_hi = AL((size_t)H_DIM*H_DIM*2), o_wo_lo = AL((size_t)H_DIM*H_DIM*2);
  size_t o_qk_hi = AL((size_t)T_TOK*H3*2),    o_qk_lo = AL((size_t)T_TOK*H3*2);
  size_t o_vt_hi = AL((size_t)16*DHEAD*S_SEQ*2), o_vt_lo = AL((size_t)16*DHEAD*S_SEQ*2);
  size_t o_at_hi = AL((size_t)T_TOK*H_DIM*2), o_at_lo = AL((size_t)T_TOK*H_DIM*2);
  // he/oew overlay phase-A region
  size_t o_he  = 0;
  size_t o_oew = (size_t)NSLOT*F_DIM*2;           // 75,497,472
  // --- persistent region ---
  size_t o_h   = AL((size_t)T_TOK*H_DIM*4);
  size_t o_ybf = AL((size_t)T_TOK*H_DIM*2);
  size_t o_re  = AL((size_t)T_TOK*2*4);
  size_t o_rwt = AL((size_t)T_TOK*2*4);
  size_t o_st  = AL((size_t)T_TOK*2*4);
  size_t o_ts  = AL((size_t)NSLOT*4);
  size_t o_wsl = AL((size_t)NSLOT*4);
  size_t o_rbe = AL(4096);
  size_t o_rbb = AL(4096);
  // --- pre-converted expert weight buffer (fast path) ---
  size_t o_wb  = AL((size_t)NEXP*F_DIM*H_DIM*2);  // 67.1 MB
  bool pre = (off_ <= ws_size);
  // --- KV-split attention partials (2 zones preferred; R5 config) ---
  size_t zone_b = (size_t)16*S_SEQ*DHEAD*4 + (size_t)16*S_SEQ*2*4;  // per-zone O + (m,l)
  size_t o_op = off_;
  bool pre2 = (o_op + 2*zone_b + 256 <= ws_size);
  (void)in_sizes; (void)n_in; (void)out_size;

  unsigned short* xa_hi = (unsigned short*)(ws+o_xa_hi);
  unsigned short* xa_lo = (unsigned short*)(ws+o_xa_lo);
  unsigned short* wq_hi = (unsigned short*)(ws+o_wq_hi);
  unsigned short* wq_lo = (unsigned short*)(ws+o_wq_lo);
  unsigned short* wo_hi = (unsigned short*)(ws+o_wo_hi);
  unsigned short* wo_lo = (unsigned short*)(ws+o_wo_lo);
  unsigned short* qk_hi = (unsigned short*)(ws+o_qk_hi);
  unsigned short* qk_lo = (unsigned short*)(ws+o_qk_lo);
  unsigned short* vt_hi = (unsigned short*)(ws+o_vt_hi);
  unsigned short* vt_lo = (unsigned short*)(ws+o_vt_lo);
  unsigned short* at_hi = (unsigned short*)(ws+o_at_hi);
  unsigned short* at_lo = (unsigned short*)(ws+o_at_lo);
  unsigned short* he    = (unsigned short*)(ws+o_he);
  float* oew   = (float*)(ws+o_oew);
  float* hbuf  = (float*)(ws+o_h);
  unsigned short* ybf = (unsigned short*)(ws+o_ybf);
  int*   route_e = (int*)(ws+o_re);
  float* route_w = (float*)(ws+o_rwt);
  int*   slot_of_tok = (int*)(ws+o_st);
  int*   tok_of_slot = (int*)(ws+o_ts);
  float* w_of_slot   = (float*)(ws+o_wsl);
  int*   rb_expert   = (int*)(ws+o_rbe);
  int*   rb_base     = (int*)(ws+o_rbb);
  unsigned short* wb = (unsigned short*)(ws+o_wb);

  // KV-split zones: 2 if partial buffers fit (R5 config), else 1 (overlay dead xa)
  int nz = pre2 ? 2 : 1;
  float* opb = (nz>1) ? (float*)(ws+o_op) : (float*)(ws+o_xa_hi);
  float* mlb = opb + (size_t)nz*16*S_SEQ*DHEAD;

  k_ln_split<<<T_TOK, 256, 0, stream>>>(x, ln1g, ln1b, xa_hi, xa_lo);
  k_wsplit<<<(H3*H_DIM/4+255)/256, 256, 0, stream>>>(wqkv, wq_hi, wq_lo, H3*H_DIM/4);
  k_wsplit<<<(H_DIM*H_DIM/4+255)/256, 256, 0, stream>>>(wout, wo_hi, wo_lo, H_DIM*H_DIM/4);
  k_gemm_split<0><<<dim3(H3/128, T_TOK/128), 256, 0, stream>>>(
      xa_hi, xa_lo, wq_hi, wq_lo, bqkv, nullptr, qk_hi, qk_lo, nullptr, H3, H_DIM);
  k_vtrans<<<dim3(S_SEQ/32, DHEAD/32, 16), 256, 0, stream>>>(qk_hi, qk_lo, vt_hi, vt_lo);
  k_attn<<<dim3(S_SEQ/128, 16, nz), 256, 0, stream>>>(qk_hi, qk_lo, vt_hi, vt_lo,
                                                      opb, mlb, S_SEQ/nz);
  k_amerge<<<dim3(S_SEQ/16, 16), 256, 0, stream>>>(opb, mlb, nz, at_hi, at_lo);
  k_gemm_split<1><<<dim3(H_DIM/128, T_TOK/128), 256, 0, stream>>>(
      at_hi, at_lo, wo_hi, wo_lo, bout, x, nullptr, nullptr, hbuf, H_DIM, H_DIM);
  k_ln2_router<<<T_TOK, 256, 0, stream>>>(hbuf, ln2g, ln2b, rw, ybf, route_e, route_w);
  k_compact<<<1, 256, 0, stream>>>(route_e, route_w, tok_of_slot, w_of_slot,
                                   slot_of_tok, rb_expert, rb_base);
  const int WN4 = NEXP*F_DIM*H_DIM/4;
  if(pre){
    k_wconv<<<(WN4+255)/256, 256, 0, stream>>>(fc1w, wb, WN4);
    k_fc<true,true><<<dim3(F_DIM/128, MAX_RB), 256, 0, stream>>>(
        ybf, fc1w, wb, fc1b, rb_expert, rb_base, tok_of_slot, nullptr, he, nullptr);
    k_wconv<<<(WN4+255)/256, 256, 0, stream>>>(fc2w, wb, WN4);
    k_fc<false,true><<<dim3(H_DIM/128, MAX_RB), 256, 0, stream>>>(
        he, fc2w, wb, fc2b, rb_expert, rb_base, tok_of_slot, w_of_slot, nullptr, oew);
  } else {
    k_fc<true,false><<<dim3(F_DIM/128, MAX_RB), 256, 0, stream>>>(
        ybf, fc1w, wb, fc1b, rb_expert, rb_base, tok_of_slot, nullptr, he, nullptr);
    k_fc<false,false><<<dim3(H_DIM/128, MAX_RB), 256, 0, stream>>>(
        he, fc2w, wb, fc2b, rb_expert, rb_base, tok_of_slot, w_of_slot, nullptr, oew);
  }
  k_combine<<<T_TOK, 256, 0, stream>>>(hbuf, oew, slot_of_tok, (float*)d_out);
}

// Round 13
// 667.659 us; speedup vs baseline: 1.0136x; 1.0136x over previous
//
#include <hip/hip_runtime.h>

#define T_TOK 4096
#define S_SEQ 2048
#define H_DIM 1024
#define H3    3072
#define NHEAD 8
#define DHEAD 128
#define F_DIM 4096
#define NEXP  8
#define MAX_RB 72
#define NSLOT 9216

typedef __bf16 bf16x8 __attribute__((ext_vector_type(8)));
typedef float  f32x4  __attribute__((ext_vector_type(4)));
typedef __attribute__((address_space(1))) const unsigned int* gas1_t;
typedef __attribute__((address_space(3))) unsigned int* las3_t;

__device__ __forceinline__ unsigned short f2bf(float f){
  unsigned int u = __builtin_bit_cast(unsigned int, f);
  u += 0x7fffu + ((u>>16)&1u);          // RTNE to bf16 (no NaN inputs here)
  return (unsigned short)(u>>16);
}
__device__ __forceinline__ float bf2f(unsigned short h){
  unsigned int u = ((unsigned int)h)<<16;
  return __builtin_bit_cast(float, u);
}
__device__ __forceinline__ f32x4 MF(bf16x8 a, bf16x8 b, f32x4 c){
  return __builtin_amdgcn_mfma_f32_16x16x32_bf16(a,b,c,0,0,0);
}
__device__ __forceinline__ void gload16(const void* g, void* l){
  __builtin_amdgcn_global_load_lds((gas1_t)g, (las3_t)l, 16, 0, 0);
}
__device__ __forceinline__ float blockReduceSum(float v){
  __shared__ float sh_red[4];
  #pragma unroll
  for(int o=32;o>0;o>>=1) v += __shfl_down(v,o,64);
  int w = threadIdx.x>>6;
  if((threadIdx.x&63)==0) sh_red[w]=v;
  __syncthreads();
  float tot = sh_red[0]+sh_red[1]+sh_red[2]+sh_red[3];
  __syncthreads();
  return tot;
}

// ---------------- LayerNorm 1: x -> xa split (bf16 hi/lo) ----------------
__global__ __launch_bounds__(256) void k_ln_split(const float* __restrict__ x,
    const float* __restrict__ g, const float* __restrict__ bta,
    unsigned short* __restrict__ hi, unsigned short* __restrict__ lo){
  int t = blockIdx.x, tid = threadIdx.x;
  float4 v = reinterpret_cast<const float4*>(x + (size_t)t*H_DIM)[tid];
  float mean = blockReduceSum(v.x+v.y+v.z+v.w) * (1.0f/H_DIM);
  float d0=v.x-mean,d1=v.y-mean,d2=v.z-mean,d3=v.w-mean;
  float var = blockReduceSum(d0*d0+d1*d1+d2*d2+d3*d3) * (1.0f/H_DIM);
  float rstd = rsqrtf(var + 1e-5f);
  float4 gv = reinterpret_cast<const float4*>(g)[tid];
  float4 bv = reinterpret_cast<const float4*>(bta)[tid];
  float o0=d0*rstd*gv.x+bv.x, o1=d1*rstd*gv.y+bv.y, o2=d2*rstd*gv.z+bv.z, o3=d3*rstd*gv.w+bv.w;
  size_t base = (size_t)t*H_DIM + tid*4;
  unsigned short h0=f2bf(o0),h1=f2bf(o1),h2=f2bf(o2),h3=f2bf(o3);
  *reinterpret_cast<ushort4*>(hi+base) = make_ushort4(h0,h1,h2,h3);
  *reinterpret_cast<ushort4*>(lo+base) = make_ushort4(
      f2bf(o0-bf2f(h0)), f2bf(o1-bf2f(h1)), f2bf(o2-bf2f(h2)), f2bf(o3-bf2f(h3)));
}

// ---------------- weight split fp32 -> bf16 hi/lo ----------------
__global__ __launch_bounds__(256) void k_wsplit(const float* __restrict__ w,
    unsigned short* __restrict__ hi, unsigned short* __restrict__ lo, int n4){
  int i = blockIdx.x*256 + threadIdx.x;
  if(i>=n4) return;
  float4 v = reinterpret_cast<const float4*>(w)[i];
  size_t base = (size_t)i*4;
  unsigned short h0=f2bf(v.x),h1=f2bf(v.y),h2=f2bf(v.z),h3=f2bf(v.w);
  *reinterpret_cast<ushort4*>(hi+base) = make_ushort4(h0,h1,h2,h3);
  *reinterpret_cast<ushort4*>(lo+base) = make_ushort4(
      f2bf(v.x-bf2f(h0)), f2bf(v.y-bf2f(h1)), f2bf(v.z-bf2f(h2)), f2bf(v.w-bf2f(h3)));
}

// ---------------- weight convert fp32 -> bf16 (hi only) ----------------
__global__ __launch_bounds__(256) void k_wconv(const float* __restrict__ w,
    unsigned short* __restrict__ hi, int n4){
  int i = blockIdx.x*256 + threadIdx.x;
  if(i>=n4) return;
  float4 v = reinterpret_cast<const float4*>(w)[i];
  *reinterpret_cast<ushort4*>(hi + (size_t)i*4) =
      make_ushort4(f2bf(v.x), f2bf(v.y), f2bf(v.z), f2bf(v.w));
}

// ---------------- split GEMM: C = A*B^T (+bias [+resid]) --------------------
template<int EPI>
__global__ __launch_bounds__(256) void k_gemm_split(
    const unsigned short* __restrict__ Ah, const unsigned short* __restrict__ Al,
    const unsigned short* __restrict__ Bh, const unsigned short* __restrict__ Bl,
    const float* __restrict__ bias, const float* __restrict__ resid,
    unsigned short* __restrict__ Chi, unsigned short* __restrict__ Clo,
    float* __restrict__ Cf, int N, int Kd){
  int m0 = blockIdx.y*128, n0 = blockIdx.x*128;
  int tid=threadIdx.x, wid=tid>>6, lane=tid&63, lr=lane&15, lg=lane>>4;
  int wr=wid>>1, wc=wid&1;
  __shared__ unsigned short tAh[4096], tAl[4096], tBh[4096], tBl[4096];
  f32x4 acc[4][4] = {};
  for(int k0=0;k0<Kd;k0+=32){
    #pragma unroll
    for(int i=0;i<2;i++){
      int p = i*256 + tid;
      int row = p>>2, pc = p&3;
      int lc = pc ^ ((row>>1)&3);                    // source pre-swizzle (rule #21)
      size_t go = (size_t)row*Kd + k0 + lc*8;
      int lb = (i*256 + wid*64)*8;
      gload16(Ah + (size_t)m0*Kd + go, tAh + lb);
      gload16(Al + (size_t)m0*Kd + go, tAl + lb);
      gload16(Bh + (size_t)n0*Kd + go, tBh + lb);
      gload16(Bl + (size_t)n0*Kd + go, tBl + lb);
    }
    asm volatile("s_waitcnt vmcnt(0)" ::: "memory");
    __syncthreads();
    bf16x8 ah[4], al[4], bh[4], bl[4];
    #pragma unroll
    for(int q=0;q<4;q++){
      int ra = wr*64+q*16+lr;
      int ia = ra*32 + ((lg ^ ((ra>>1)&3))<<3);
      ah[q] = *reinterpret_cast<const bf16x8*>(&tAh[ia]);
      al[q] = *reinterpret_cast<const bf16x8*>(&tAl[ia]);
      int rb = wc*64+q*16+lr;
      int ib = rb*32 + ((lg ^ ((rb>>1)&3))<<3);
      bh[q] = *reinterpret_cast<const bf16x8*>(&tBh[ib]);
      bl[q] = *reinterpret_cast<const bf16x8*>(&tBl[ib]);
    }
    #pragma unroll
    for(int mf=0;mf<4;mf++)
      #pragma unroll
      for(int nf=0;nf<4;nf++){
        acc[mf][nf] = MF(ah[mf], bh[nf], acc[mf][nf]);
        acc[mf][nf] = MF(ah[mf], bl[nf], acc[mf][nf]);
        acc[mf][nf] = MF(al[mf], bh[nf], acc[mf][nf]);
      }
    __syncthreads();
  }
  #pragma unroll
  for(int mf=0;mf<4;mf++)
    #pragma unroll
    for(int nf=0;nf<4;nf++)
      #pragma unroll
      for(int r=0;r<4;r++){
        int row = m0 + wr*64 + mf*16 + lg*4 + r;
        int col = n0 + wc*64 + nf*16 + lr;
        float v = acc[mf][nf][r] + bias[col];
        size_t idx = (size_t)row*N + col;
        if(EPI==0){
          unsigned short hb = f2bf(v);
          Chi[idx]=hb; Clo[idx]=f2bf(v-bf2f(hb));
        } else {
          Cf[idx] = v + resid[idx];
        }
      }
}

// ---------------- V transpose: qkv v-cols -> vt[bh][d][s] hi/lo ----------------
__global__ __launch_bounds__(256) void k_vtrans(const unsigned short* __restrict__ qh,
    const unsigned short* __restrict__ ql,
    unsigned short* __restrict__ vth, unsigned short* __restrict__ vtl){
  int bh = blockIdx.z, d0 = blockIdx.y*32, s0 = blockIdx.x*32;
  int b = bh>>3, hh = bh&7;
  int tid=threadIdx.x;
  __shared__ unsigned short th[32][40], tl[32][40];
  int sr = tid>>3, dc = (tid&7)*4;
  size_t src = ((size_t)(b*S_SEQ + s0 + sr))*H3 + 2*H_DIM + hh*DHEAD + d0 + dc;
  *reinterpret_cast<ushort4*>(&th[sr][dc]) = *reinterpret_cast<const ushort4*>(qh+src);
  *reinterpret_cast<ushort4*>(&tl[sr][dc]) = *reinterpret_cast<const ushort4*>(ql+src);
  __syncthreads();
  int dr = tid>>3, sc = (tid&7)*4;
  size_t dst = ((size_t)(bh*DHEAD) + d0+dr)*S_SEQ + s0 + sc;
  *reinterpret_cast<ushort4*>(vth+dst) = make_ushort4(th[sc][dr],th[sc+1][dr],th[sc+2][dr],th[sc+3][dr]);
  *reinterpret_cast<ushort4*>(vtl+dst) = make_ushort4(tl[sc][dr],tl[sc+1][dr],tl[sc+2][dr],tl[sc+3][dr]);
}

// ---------------- flash attention (split precision, swapped-QK, KV-split partials) ----------------
// Single-buffered 48 KB LDS so 2 blocks co-reside per CU (cross-block latency hiding).
__global__ __launch_bounds__(256,2) void k_attn(const unsigned short* __restrict__ qkv_hi,
    const unsigned short* __restrict__ qkv_lo,
    const unsigned short* __restrict__ vt_hi, const unsigned short* __restrict__ vt_lo,
    float* __restrict__ opb, float* __restrict__ mlb, int kv_span){
  const float SCALE = 0.08838834764831843f;   // 1/sqrt(128)
  int qb = blockIdx.x, bh = blockIdx.y, zz = blockIdx.z;
  int b = bh>>3, hh = bh&7;
  int kvbase = zz*kv_span, kvend = kvbase + kv_span;
  int tid=threadIdx.x, wid=tid>>6, lane=tid&63, lr=lane&15, lg=lane>>4;
  __shared__ unsigned short kh[4096], kl[4096], vh[4096], vl[4096];   // 32 KB
  __shared__ unsigned short ph[4][1024], pl[4][1024];                 // 16 KB
  int row0 = qb*128 + wid*32;            // wave's first q row (wave owns 32 rows)
  // Q fragments in registers: B-operand layout (col=qrow=lr, k-slice lg*8)
  bf16x8 qh_[2][4], ql_[2][4];
  #pragma unroll
  for(int j=0;j<2;j++){
    size_t qbase = ((size_t)(b*S_SEQ) + row0 + j*16 + lr)*H3 + hh*DHEAD;
    #pragma unroll
    for(int kk=0;kk<4;kk++){
      qh_[j][kk] = *reinterpret_cast<const bf16x8*>(qkv_hi + qbase + kk*32 + lg*8);
      ql_[j][kk] = *reinterpret_cast<const bf16x8*>(qkv_lo + qbase + kk*32 + lg*8);
    }
  }
  f32x4 o_acc[2][8] = {};
  float mrun[2] = {-1e30f,-1e30f};
  float lrun[2] = {0.f,0.f};

  auto STAGE = [&](int kv0){
    #pragma unroll
    for(int i=0;i<2;i++){
      int p = i*256 + tid;
      int lb = (i*256 + wid*64)*8;
      { // K tile [32 keys][128 d], 16B-chunk XOR source pre-swizzle
        int krow = p>>4, pc = p&15;
        int lc = (pc&8)|((pc&7)^(krow&7));
        size_t go = ((size_t)(b*S_SEQ + kv0 + krow))*H3 + H_DIM + hh*DHEAD + lc*8;
        gload16(qkv_hi + go, &kh[lb]);
        gload16(qkv_lo + go, &kl[lb]);
      }
      { // V tile [128 d][32 keys]
        int vrow = p>>2, pc = p&3;
        int lc = pc ^ ((vrow>>1)&3);
        size_t gv = ((size_t)(bh*DHEAD) + vrow)*S_SEQ + kv0 + lc*8;
        gload16(vt_hi + gv, &vh[lb]);
        gload16(vt_lo + gv, &vl[lb]);
      }
    }
  };

  for(int kv0=kvbase; kv0<kvend; kv0+=32){
    STAGE(kv0);
    asm volatile("s_waitcnt vmcnt(0)" ::: "memory");
    __syncthreads();
    // ---- QK^T swapped: S[key][qrow] = mfma(K, Q), split 3-product ----
    f32x4 s0[2] = {}, s1[2] = {};              // keys 0-15 / 16-31, per q-block
    #pragma unroll
    for(int kk=0;kk<4;kk++){
      int c = kk*4+lg;
      int phys = (c&8)|((c&7)^(lr&7));
      bf16x8 kah = *reinterpret_cast<const bf16x8*>(&kh[lr*128 + phys*8]);
      bf16x8 kal = *reinterpret_cast<const bf16x8*>(&kl[lr*128 + phys*8]);
      bf16x8 kbh = *reinterpret_cast<const bf16x8*>(&kh[(16+lr)*128 + phys*8]);
      bf16x8 kbl = *reinterpret_cast<const bf16x8*>(&kl[(16+lr)*128 + phys*8]);
      #pragma unroll
      for(int j=0;j<2;j++){
        s0[j] = MF(kah, qh_[j][kk], s0[j]);
        s0[j] = MF(kah, ql_[j][kk], s0[j]);
        s0[j] = MF(kal, qh_[j][kk], s0[j]);
        s1[j] = MF(kbh, qh_[j][kk], s1[j]);
        s1[j] = MF(kbh, ql_[j][kk], s1[j]);
        s1[j] = MF(kbl, qh_[j][kk], s1[j]);
      }
    }
    // ---- online softmax: lane owns qrow=lr, 8 keys in regs ----
    float sc[2][8]; float mt[2];
    #pragma unroll
    for(int j=0;j<2;j++){
      #pragma unroll
      for(int r=0;r<4;r++){ sc[j][r] = s0[j][r]*SCALE; sc[j][4+r] = s1[j][r]*SCALE; }
      float m_ = fmaxf(fmaxf(fmaxf(sc[j][0],sc[j][1]),fmaxf(sc[j][2],sc[j][3])),
                       fmaxf(fmaxf(sc[j][4],sc[j][5]),fmaxf(sc[j][6],sc[j][7])));
      m_ = fmaxf(m_, __shfl_xor(m_,16,64));
      m_ = fmaxf(m_, __shfl_xor(m_,32,64));
      mt[j] = m_;
    }
    // defer-max (T13): skip O-rescale unless tile max grew past threshold
    int skip = __all((mt[0] <= mrun[0]+8.0f) && (mt[1] <= mrun[1]+8.0f));
    if(!skip){
      #pragma unroll
      for(int j=0;j<2;j++){
        float mn = fmaxf(mrun[j], mt[j]);
        float rs = __expf(mrun[j]-mn);
        lrun[j] *= rs; mrun[j] = mn;
        #pragma unroll
        for(int nf2=0;nf2<8;nf2++){
          f32x4 t = o_acc[j][nf2];
          t[0]*=rs; t[1]*=rs; t[2]*=rs; t[3]*=rs;
          o_acc[j][nf2] = t;
        }
      }
    }
    #pragma unroll
    for(int j=0;j<2;j++){
      float ssum = 0.f;
      #pragma unroll
      for(int i=0;i<8;i++){ sc[j][i] = __expf(sc[j][i]-mrun[j]); ssum += sc[j][i]; }
      ssum += __shfl_xor(ssum,16,64);
      ssum += __shfl_xor(ssum,32,64);
      lrun[j] += ssum;
      // pack P hi/lo, swizzled b64 writes: row qrow=lr, keys lg*4..+3 and 16+lg*4..+3
      unsigned short hbk[8], lbk[8];
      #pragma unroll
      for(int i=0;i<8;i++){ hbk[i]=f2bf(sc[j][i]); lbk[i]=f2bf(sc[j][i]-bf2f(hbk[i])); }
      int half = (lg&1)*4;
      int a0 = j*512 + lr*32 + (((lg>>1)^(lr&3))<<3) + half;
      int a1 = j*512 + lr*32 + ((((lg>>1)+2)^(lr&3))<<3) + half;
      *reinterpret_cast<ushort4*>(&ph[wid][a0]) = make_ushort4(hbk[0],hbk[1],hbk[2],hbk[3]);
      *reinterpret_cast<ushort4*>(&pl[wid][a0]) = make_ushort4(lbk[0],lbk[1],lbk[2],lbk[3]);
      *reinterpret_cast<ushort4*>(&ph[wid][a1]) = make_ushort4(hbk[4],hbk[5],hbk[6],hbk[7]);
      *reinterpret_cast<ushort4*>(&pl[wid][a1]) = make_ushort4(lbk[4],lbk[5],lbk[6],lbk[7]);
    }
    // ---- PV: O^T[d][qrow] = mfma(V, P), split 3-product ----
    bf16x8 pbh[2], pbl[2];
    #pragma unroll
    for(int j=0;j<2;j++){
      int pp = (lg^(lr&3))<<3;
      pbh[j] = *reinterpret_cast<const bf16x8*>(&ph[wid][j*512 + lr*32 + pp]);
      pbl[j] = *reinterpret_cast<const bf16x8*>(&pl[wid][j*512 + lr*32 + pp]);
    }
    #pragma unroll
    for(int nf2=0;nf2<8;nf2++){
      int d = nf2*16 + lr;
      int vp = (lg ^ ((d>>1)&3))<<3;
      bf16x8 vah = *reinterpret_cast<const bf16x8*>(&vh[d*32 + vp]);
      bf16x8 val = *reinterpret_cast<const bf16x8*>(&vl[d*32 + vp]);
      #pragma unroll
      for(int j=0;j<2;j++){
        o_acc[j][nf2] = MF(vah, pbh[j], o_acc[j][nf2]);
        o_acc[j][nf2] = MF(vah, pbl[j], o_acc[j][nf2]);
        o_acc[j][nf2] = MF(val, pbh[j], o_acc[j][nf2]);
      }
    }
    __syncthreads();   // all reads of kh/kl/vh/vl done before next STAGE overwrites
  }
  // ---- epilogue: write unnormalized fp32 partials + (m,l) per row ----
  #pragma unroll
  for(int j=0;j<2;j++){
    int srow = row0 + j*16 + lr;
    size_t obase = (((size_t)zz*16 + bh)*S_SEQ + srow)*(size_t)DHEAD;
    #pragma unroll
    for(int nf2=0;nf2<8;nf2++){
      *reinterpret_cast<f32x4*>(&opb[obase + nf2*16 + lg*4]) = o_acc[j][nf2];
    }
    if(lg==0){
      *reinterpret_cast<float2*>(&mlb[(((size_t)zz*16 + bh)*S_SEQ + srow)*2]) =
          make_float2(mrun[j], lrun[j]);
    }
  }
}

// ---------------- merge KV-split partials -> attn out (bf16 hi/lo) ----------------
__global__ __launch_bounds__(256) void k_amerge(const float* __restrict__ opb,
    const float* __restrict__ mlb, int nz,
    unsigned short* __restrict__ o_hi, unsigned short* __restrict__ o_lo){
  int bh = blockIdx.y, b = bh>>3, hh = bh&7;
  int r = threadIdx.x>>4;                 // 0..15 row within block
  int c = (threadIdx.x&15)*8;             // 0..120 col (d)
  int srow = blockIdx.x*16 + r;
  float mz[4], lz[4];
  float m = -1e30f;
  for(int z=0;z<nz;z++){
    const float* mlp = mlb + (((size_t)z*16 + bh)*S_SEQ + srow)*2;
    mz[z]=mlp[0]; lz[z]=mlp[1];
    m = fmaxf(m, mz[z]);
  }
  float L = 0.f, w[4];
  for(int z=0;z<nz;z++){ w[z] = __expf(mz[z]-m); L += lz[z]*w[z]; }
  float linv = 1.0f/L;
  float acc[8] = {0,0,0,0,0,0,0,0};
  for(int z=0;z<nz;z++){
    const float* o = opb + (((size_t)z*16 + bh)*S_SEQ + srow)*(size_t)DHEAD + c;
    float4 a = *reinterpret_cast<const float4*>(o);
    float4 bq = *reinterpret_cast<const float4*>(o+4);
    acc[0]+=a.x*w[z]; acc[1]+=a.y*w[z]; acc[2]+=a.z*w[z]; acc[3]+=a.w*w[z];
    acc[4]+=bq.x*w[z]; acc[5]+=bq.y*w[z]; acc[6]+=bq.z*w[z]; acc[7]+=bq.w*w[z];
  }
  size_t idx = ((size_t)(b*S_SEQ)+srow)*H_DIM + hh*DHEAD + c;
  unsigned short hp[8], lp[8];
  #pragma unroll
  for(int i=0;i<8;i++){
    float v = acc[i]*linv;
    hp[i]=f2bf(v); lp[i]=f2bf(v-bf2f(hp[i]));
  }
  *reinterpret_cast<ushort4*>(o_hi+idx)   = make_ushort4(hp[0],hp[1],hp[2],hp[3]);
  *reinterpret_cast<ushort4*>(o_hi+idx+4) = make_ushort4(hp[4],hp[5],hp[6],hp[7]);
  *reinterpret_cast<ushort4*>(o_lo+idx)   = make_ushort4(lp[0],lp[1],lp[2],lp[3]);
  *reinterpret_cast<ushort4*>(o_lo+idx+4) = make_ushort4(lp[4],lp[5],lp[6],lp[7]);
}

// ---------------- LayerNorm 2 + router ----------------
__global__ __launch_bounds__(256) void k_ln2_router(const float* __restrict__ h,
    const float* __restrict__ g, const float* __restrict__ bt, const float* __restrict__ rw,
    unsigned short* __restrict__ ybf, int* __restrict__ route_e, float* __restrict__ route_w){
  int t = blockIdx.x, tid = threadIdx.x;
  float4 v = reinterpret_cast<const float4*>(h + (size_t)t*H_DIM)[tid];
  float mean = blockReduceSum(v.x+v.y+v.z+v.w) * (1.0f/H_DIM);
  float d0=v.x-mean,d1=v.y-mean,d2=v.z-mean,d3=v.w-mean;
  float var = blockReduceSum(d0*d0+d1*d1+d2*d2+d3*d3) * (1.0f/H_DIM);
  float rstd = rsqrtf(var + 1e-5f);
  float4 gv = reinterpret_cast<const float4*>(g)[tid];
  float4 bv = reinterpret_cast<const float4*>(bt)[tid];
  float o0=d0*rstd*gv.x+bv.x, o1=d1*rstd*gv.y+bv.y, o2=d2*rstd*gv.z+bv.z, o3=d3*rstd*gv.w+bv.w;
  size_t base = (size_t)t*H_DIM + tid*4;
  *reinterpret_cast<ushort4*>(ybf+base) = make_ushort4(f2bf(o0),f2bf(o1),f2bf(o2),f2bf(o3));
  float part[8];
  #pragma unroll
  for(int e=0;e<8;e++){
    float4 r = reinterpret_cast<const float4*>(rw + e*H_DIM)[tid];
    part[e] = o0*r.x + o1*r.y + o2*r.z + o3*r.w;
  }
  __shared__ float sm[32];
  #pragma unroll
  for(int e=0;e<8;e++){
    float p = part[e];
    #pragma unroll
    for(int o=32;o>0;o>>=1) p += __shfl_down(p,o,64);
    if((tid&63)==0) sm[(tid>>6)*8+e] = p;
  }
  __syncthreads();
  if(tid==0){
    float lgt[8];
    #pragma unroll
    for(int e=0;e<8;e++) lgt[e] = sm[e]+sm[8+e]+sm[16+e]+sm[24+e];
    float mx = lgt[0];
    #pragma unroll
    for(int e=1;e<8;e++) mx = fmaxf(mx, lgt[e]);
    float ex[8], ssum=0.f;
    #pragma unroll
    for(int e=0;e<8;e++){ ex[e]=__expf(lgt[e]-mx); ssum+=ex[e]; }
    float inv = 1.0f/ssum;
    int e0=0; float p0=ex[0];
    for(int e=1;e<8;e++) if(ex[e]>p0){p0=ex[e];e0=e;}
    int e1=-1; float p1=-1.0f;
    for(int e=0;e<8;e++) if(e!=e0 && ex[e]>p1){p1=ex[e];e1=e;}
    route_e[2*t]=e0; route_e[2*t+1]=e1;
    route_w[2*t]=p0*inv; route_w[2*t+1]=p1*inv;
  }
}

// ---------------- routing compaction (single block) ----------------
__global__ __launch_bounds__(256) void k_compact(const int* __restrict__ route_e,
    const float* __restrict__ route_w, int* __restrict__ tok_of_slot,
    float* __restrict__ w_of_slot, int* __restrict__ slot_of_tok,
    int* __restrict__ rb_expert, int* __restrict__ rb_base){
  __shared__ int cnt[8], off[8], pos[8];
  int tid = threadIdx.x;
  if(tid<8){ cnt[tid]=0; pos[tid]=0; }
  __syncthreads();
  for(int t=tid;t<T_TOK;t+=256){
    atomicAdd(&cnt[route_e[2*t]],1);
    atomicAdd(&cnt[route_e[2*t+1]],1);
  }
  __syncthreads();
  if(tid==0){
    int o=0;
    for(int e=0;e<8;e++){ off[e]=o; o += ((cnt[e]+127)>>7)<<7; }
    int rb=0;
    for(int e=0;e<8;e++){
      int nrb = (cnt[e]+127)>>7;
      for(int r=0;r<nrb;r++){ rb_expert[rb]=e; rb_base[rb]=off[e]+r*128; rb++; }
    }
    for(;rb<MAX_RB;rb++){ rb_expert[rb]=-1; rb_base[rb]=0; }
  }
  __syncthreads();
  for(int s=tid;s<NSLOT;s+=256){ tok_of_slot[s]=0; w_of_slot[s]=0.0f; }
  __syncthreads();
  for(int t=tid;t<T_TOK;t+=256){
    int e0=route_e[2*t], e1=route_e[2*t+1];
    int s0 = off[e0] + atomicAdd(&pos[e0],1);
    tok_of_slot[s0]=t; w_of_slot[s0]=route_w[2*t]; slot_of_tok[2*t]=s0;
    int s1 = off[e1] + atomicAdd(&pos[e1],1);
    tok_of_slot[s1]=t; w_of_slot[s1]=route_w[2*t+1]; slot_of_tok[2*t+1]=s1;
  }
}

// ---------------- expert GEMMs (R5 inner loop; fc2 gets XCD-grouping dispatch remap) ----------------
template<bool FC1, bool PRE>
__global__ __launch_bounds__(256) void k_fc(const unsigned short* __restrict__ Abuf,
    const float* __restrict__ W, const unsigned short* __restrict__ Wbf,
    const float* __restrict__ bias,
    const int* __restrict__ rb_expert, const int* __restrict__ rb_base,
    const int* __restrict__ tok_of_slot, const float* __restrict__ w_of_slot,
    unsigned short* __restrict__ he_out, float* __restrict__ oew_out){
  int rb, n0;
  if(FC1){
    rb = blockIdx.y; n0 = blockIdx.x*128;
  } else {
    // fc2: remap dispatch index so all 8 n-blocks of a rowblock hit the SAME XCD
    // (round-robin XCD assignment by dispatch order; grid = 8 x 72).
    int lin = blockIdx.y*8 + blockIdx.x;   // dispatch-order index (x fastest)
    int xcd = lin & 7;
    int rest = lin >> 3;
    int nn = rest & 7;
    int rq = rest >> 3;                    // 0..8
    rb = rq*8 + xcd;                       // rowblock; all its n-blocks share xcd
    n0 = nn*128;
  }
  int e = rb_expert[rb];
  if(e<0) return;
  int base = rb_base[rb];
  const int Kd = FC1 ? H_DIM : F_DIM;
  const int Nd = FC1 ? F_DIM : H_DIM;
  int tid=threadIdx.x, wid=tid>>6, lane=tid&63, lr=lane&15, lg=lane>>4;
  int wr=wid>>1, wc=wid&1;
  __shared__ unsigned short tA[4096], tB[4096];
  size_t arow_src[2];
  #pragma unroll
  for(int i=0;i<2;i++){
    int row = i*64 + (tid>>2);
    if(FC1){ int tok = tok_of_slot[base+row]; arow_src[i] = (size_t)tok*H_DIM; }
    else   { arow_src[i] = (size_t)(base+row)*F_DIM; }
  }
  const float* Wp = W + (size_t)e*F_DIM*H_DIM;
  const unsigned short* Wbp = Wbf + (size_t)e*F_DIM*H_DIM;
  f32x4 acc[4][4] = {};
  for(int k0=0;k0<Kd;k0+=32){
    #pragma unroll
    for(int i=0;i<2;i++){
      int p = i*256+tid; int row=p>>2, pc=p&3;
      int lc = pc ^ ((row>>1)&3);
      gload16(Abuf + arow_src[i] + k0 + lc*8, tA + (i*256+wid*64)*8);
      if(PRE){
        gload16(Wbp + (size_t)(n0+row)*Kd + k0 + lc*8, tB + (i*256+wid*64)*8);
      }
    }
    if(!PRE){
      #pragma unroll
      for(int j=0;j<4;j++){
        int f = tid*16 + j*4; int row=f>>5; int kin=f&31;
        float4 wv = *reinterpret_cast<const float4*>(Wp + (size_t)(n0+row)*Kd + k0 + kin);
        int c16 = kin>>3, half=(kin>>2)&1;
        int phys = c16 ^ ((row>>1)&3);
        *reinterpret_cast<ushort4*>(&tB[row*32 + phys*8 + half*4]) =
            make_ushort4(f2bf(wv.x), f2bf(wv.y), f2bf(wv.z), f2bf(wv.w));
      }
    }
    asm volatile("s_waitcnt vmcnt(0)" ::: "memory");
    __syncthreads();
    bf16x8 af[4], bfr[4];
    #pragma unroll
    for(int q=0;q<4;q++){
      int ra = wr*64+q*16+lr;
      af[q] = *reinterpret_cast<const bf16x8*>(&tA[ra*32 + ((lg ^ ((ra>>1)&3))<<3)]);
      int rbw = wc*64+q*16+lr;
      bfr[q] = *reinterpret_cast<const bf16x8*>(&tB[rbw*32 + ((lg ^ ((rbw>>1)&3))<<3)]);
    }
    #pragma unroll
    for(int mf=0;mf<4;mf++)
      #pragma unroll
      for(int nf=0;nf<4;nf++)
        acc[mf][nf] = MF(af[mf], bfr[nf], acc[mf][nf]);
    __syncthreads();
  }
  #pragma unroll
  for(int mf=0;mf<4;mf++)
    #pragma unroll
    for(int nf=0;nf<4;nf++)
      #pragma unroll
      for(int r=0;r<4;r++){
        int lrow = wr*64+mf*16+lg*4+r;
        int col = n0 + wc*64+nf*16+lr;
        float v = acc[mf][nf][r] + bias[(size_t)e*Nd + col];
        if(FC1){
          float sv = v/(1.0f+__expf(-v));          // silu
          he_out[(size_t)(base+lrow)*F_DIM + col] = f2bf(sv);
        } else {
          oew_out[(size_t)(base+lrow)*H_DIM + col] = w_of_slot[base+lrow]*v;
        }
      }
}

// ---------------- combine: out = h + oe[slot0] + oe[slot1] ----------------
__global__ __launch_bounds__(256) void k_combine(const float* __restrict__ h,
    const float* __restrict__ oew, const int* __restrict__ slot_of_tok,
    float* __restrict__ out){
  int t = blockIdx.x, tid=threadIdx.x;
  int s0 = slot_of_tok[2*t], s1 = slot_of_tok[2*t+1];
  float4 hv = reinterpret_cast<const float4*>(h + (size_t)t*H_DIM)[tid];
  float4 a = reinterpret_cast<const float4*>(oew + (size_t)s0*H_DIM)[tid];
  float4 b = reinterpret_cast<const float4*>(oew + (size_t)s1*H_DIM)[tid];
  float4 o = make_float4(hv.x+a.x+b.x, hv.y+a.y+b.y, hv.z+a.z+b.z, hv.w+a.w+b.w);
  reinterpret_cast<float4*>(out + (size_t)t*H_DIM)[tid] = o;
}

extern "C" void kernel_launch(void* const* d_in, const int* in_sizes, int n_in,
                              void* d_out, int out_size, void* d_ws, size_t ws_size,
                              hipStream_t stream){
  const float* x    = (const float*)d_in[0];
  const float* ln1g = (const float*)d_in[1];
  const float* ln1b = (const float*)d_in[2];
  const float* ln2g = (const float*)d_in[3];
  const float* ln2b = (const float*)d_in[4];
  const float* wqkv = (const float*)d_in[5];
  const float* bqkv = (const float*)d_in[6];
  const float* wout = (const float*)d_in[7];
  const float* bout = (const float*)d_in[8];
  const float* rw   = (const float*)d_in[9];
  const float* fc1w = (const float*)d_in[10];
  const float* fc1b = (const float*)d_in[11];
  const float* fc2w = (const float*)d_in[12];
  const float* fc2b = (const float*)d_in[13];
  char* ws = (char*)d_ws;

  size_t off_ = 0;
  auto AL = [&](size_t bytes){ size_t r = off_; off_ = (off_ + bytes + 255) & ~(size_t)255; return r; };
  // --- phase-A region (dead before MoE) ---
  size_t o_xa_hi = AL((size_t)T_TOK*H_DIM*2), o_xa_lo = AL((size_t)T_TOK*H_DIM*2);
  size_t o_wq_hi = AL((size_t)H3*H_DIM*2),    o_wq_lo = AL((size_t)H3*H_DIM*2);
  size_t o_wo_hi = AL((size_t)H_DIM*H_DIM*2), o_wo_lo = AL((size_t)H_DIM*H_DIM*2);
  size_t o_qk_hi = AL((size_t)T_TOK*H3*2),    o_qk_lo = AL((size_t)T_TOK*H3*2);
  size_t o_vt_hi = AL((size_t)16*DHEAD*S_SEQ*2), o_vt_lo = AL((size_t)16*DHEAD*S_SEQ*2);
  size_t o_at_hi = AL((size_t)T_TOK*H_DIM*2), o_at_lo = AL((size_t)T_TOK*H_DIM*2);
  // he/oew overlay phase-A region
  size_t o_he  = 0;
  size_t o_oew = (size_t)NSLOT*F_DIM*2;           // 75,497,472
  // --- persistent region ---
  size_t o_h   = AL((size_t)T_TOK*H_DIM*4);
  size_t o_ybf = AL((size_t)T_TOK*H_DIM*2);
  size_t o_re  = AL((size_t)T_TOK*2*4);
  size_t o_rwt = AL((size_t)T_TOK*2*4);
  size_t o_st  = AL((size_t)T_TOK*2*4);
  size_t o_ts  = AL((size_t)NSLOT*4);
  size_t o_wsl = AL((size_t)NSLOT*4);
  size_t o_rbe = AL(4096);
  size_t o_rbb = AL(4096);
  // --- pre-converted expert weight buffer (fast path) ---
  size_t o_wb  = AL((size_t)NEXP*F_DIM*H_DIM*2);  // 67.1 MB
  bool pre = (off_ <= ws_size);
  // --- KV-split attention partials (2 zones preferred; R5 config) ---
  size_t zone_b = (size_t)16*S_SEQ*DHEAD*4 + (size_t)16*S_SEQ*2*4;  // per-zone O + (m,l)
  size_t o_op = off_;
  bool pre2 = (o_op + 2*zone_b + 256 <= ws_size);
  (void)in_sizes; (void)n_in; (void)out_size;

  unsigned short* xa_hi = (unsigned short*)(ws+o_xa_hi);
  unsigned short* xa_lo = (unsigned short*)(ws+o_xa_lo);
  unsigned short* wq_hi = (unsigned short*)(ws+o_wq_hi);
  unsigned short* wq_lo = (unsigned short*)(ws+o_wq_lo);
  unsigned short* wo_hi = (unsigned short*)(ws+o_wo_hi);
  unsigned short* wo_lo = (unsigned short*)(ws+o_wo_lo);
  unsigned short* qk_hi = (unsigned short*)(ws+o_qk_hi);
  unsigned short* qk_lo = (unsigned short*)(ws+o_qk_lo);
  unsigned short* vt_hi = (unsigned short*)(ws+o_vt_hi);
  unsigned short* vt_lo = (unsigned short*)(ws+o_vt_lo);
  unsigned short* at_hi = (unsigned short*)(ws+o_at_hi);
  unsigned short* at_lo = (unsigned short*)(ws+o_at_lo);
  unsigned short* he    = (unsigned short*)(ws+o_he);
  float* oew   = (float*)(ws+o_oew);
  float* hbuf  = (float*)(ws+o_h);
  unsigned short* ybf = (unsigned short*)(ws+o_ybf);
  int*   route_e = (int*)(ws+o_re);
  float* route_w = (float*)(ws+o_rwt);
  int*   slot_of_tok = (int*)(ws+o_st);
  int*   tok_of_slot = (int*)(ws+o_ts);
  float* w_of_slot   = (float*)(ws+o_wsl);
  int*   rb_expert   = (int*)(ws+o_rbe);
  int*   rb_base     = (int*)(ws+o_rbb);
  unsigned short* wb = (unsigned short*)(ws+o_wb);

  // KV-split zones: 2 if partial buffers fit (R5 config), else 1 (overlay dead xa)
  int nz = pre2 ? 2 : 1;
  float* opb = (nz>1) ? (float*)(ws+o_op) : (float*)(ws+o_xa_hi);
  float* mlb = opb + (size_t)nz*16*S_SEQ*DHEAD;

  k_ln_split<<<T_TOK, 256, 0, stream>>>(x, ln1g, ln1b, xa_hi, xa_lo);
  k_wsplit<<<(H3*H_DIM/4+255)/256, 256, 0, stream>>>(wqkv, wq_hi, wq_lo, H3*H_DIM/4);
  k_wsplit<<<(H_DIM*H_DIM/4+255)/256, 256, 0, stream>>>(wout, wo_hi, wo_lo, H_DIM*H_DIM/4);
  k_gemm_split<0><<<dim3(H3/128, T_TOK/128), 256, 0, stream>>>(
      xa_hi, xa_lo, wq_hi, wq_lo, bqkv, nullptr, qk_hi, qk_lo, nullptr, H3, H_DIM);
  k_vtrans<<<dim3(S_SEQ/32, DHEAD/32, 16), 256, 0, stream>>>(qk_hi, qk_lo, vt_hi, vt_lo);
  k_attn<<<dim3(S_SEQ/128, 16, nz), 256, 0, stream>>>(qk_hi, qk_lo, vt_hi, vt_lo,
                                                      opb, mlb, S_SEQ/nz);
  k_amerge<<<dim3(S_SEQ/16, 16), 256, 0, stream>>>(opb, mlb, nz, at_hi, at_lo);
  k_gemm_split<1><<<dim3(H_DIM/128, T_TOK/128), 256, 0, stream>>>(
      at_hi, at_lo, wo_hi, wo_lo, bout, x, nullptr, nullptr, hbuf, H_DIM, H_DIM);
  k_ln2_router<<<T_TOK, 256, 0, stream>>>(hbuf, ln2g, ln2b, rw, ybf, route_e, route_w);
  k_compact<<<1, 256, 0, stream>>>(route_e, route_w, tok_of_slot, w_of_slot,
                                   slot_of_tok, rb_expert, rb_base);
  const int WN4 = NEXP*F_DIM*H_DIM/4;
  if(pre){
    k_wconv<<<(WN4+255)/256, 256, 0, stream>>>(fc1w, wb, WN4);
    k_fc<true,true><<<dim3(F_DIM/128, MAX_RB), 256, 0, stream>>>(
        ybf, fc1w, wb, fc1b, rb_expert, rb_base, tok_of_slot, nullptr, he, nullptr);
    k_wconv<<<(WN4+255)/256, 256, 0, stream>>>(fc2w, wb, WN4);
    k_fc<false,true><<<dim3(H_DIM/128, MAX_RB), 256, 0, stream>>>(
        he, fc2w, wb, fc2b, rb_expert, rb_base, tok_of_slot, w_of_slot, nullptr, oew);
  } else {
    k_fc<true,false><<<dim3(F_DIM/128, MAX_RB), 256, 0, stream>>>(
        ybf, fc1w, wb, fc1b, rb_expert, rb_base, tok_of_slot, nullptr, he, nullptr);
    k_fc<false,false><<<dim3(H_DIM/128, MAX_RB), 256, 0, stream>>>(
        he, fc2w, wb, fc2b, rb_expert, rb_base, tok_of_slot, w_of_slot, nullptr, oew);
  }
  k_combine<<<T_TOK, 256, 0, stream>>>(hbuf, oew, slot_of_tok, (float*)d_out);
}